// Round 1
// baseline (104.424 us; speedup 1.0000x reference)
//
#include <hip/hip_runtime.h>

// GNN1: drug-relation GNN layer, MI355X (gfx950).
// Structure:
//   b2sum_kernel : b2sum[k] = sum_e b2[k,e]                       (4 blocks)
//   fused_gnn    : per-drug block: w2sum, W1 hi/lo split -> LDS,
//                  split-bf16 MFMA GEMM (1024x64x64), +b1/relu/dot w2sum,
//                  softmax over K, weighted ent gather, final linear -> y (ws)
//   bn_kernel    : BatchNorm1d (training stats) over N=846 -> out  (64 blocks)

#define NDRUG 846
#define KNB   1024
#define BN_EPS 1e-5f

typedef __attribute__((ext_vector_type(8))) short short8;
typedef __attribute__((ext_vector_type(4))) float f32x4;

__device__ __forceinline__ unsigned short f2bf(float x){
    unsigned u = __float_as_uint(x);
    unsigned r = u + 0x7fffu + ((u >> 16) & 1u);
    return (unsigned short)(r >> 16);
}
__device__ __forceinline__ float bf2f(unsigned short h){
    return __uint_as_float(((unsigned)h) << 16);
}

__global__ void b2sum_kernel(const float* __restrict__ b2, float* __restrict__ b2s){
    int k = blockIdx.x*256 + threadIdx.x;
    const float4* p = (const float4*)(b2 + (size_t)k*64);
    float s = 0.f;
    #pragma unroll
    for (int i = 0; i < 16; ++i){ float4 v = p[i]; s += v.x+v.y+v.z+v.w; }
    b2s[k] = s;
}

__global__ __launch_bounds__(256,2) void fused_gnn(
    const float* __restrict__ drug_table, const float* __restrict__ rela_table,
    const float* __restrict__ ent_table,  const float* __restrict__ W1,
    const float* __restrict__ b1,         const float* __restrict__ W2,
    const float* __restrict__ lin_w,      const float* __restrict__ lin_b,
    const int* __restrict__ drug_name,    const int* __restrict__ adj_tail,
    const int* __restrict__ adj_rel,      const float* __restrict__ b2sum,
    float* __restrict__ y_out)
{
    __shared__ unsigned short Bh[4096], Bl[4096]; // W1 split, fragment-linear
    __shared__ float scores[KNB];
    __shared__ float w2s[64];
    __shared__ float drug[64];
    __shared__ float red[256];
    __shared__ float wepart[4][64];
    __shared__ float de[128];

    const int t = threadIdx.x;
    const int lane = t & 63;
    const int w = t >> 6;
    const int n = blockIdx.x;

    if (t < 64) drug[t] = drug_table[(size_t)drug_name[n]*64 + t];

    { // w2sum partials: thread t covers W2[n] floats [t*16, t*16+16)
        const float4* W2v = (const float4*)(W2 + (size_t)n*4096);
        float s = 0.f;
        #pragma unroll
        for (int i = 0; i < 4; ++i){ float4 v = W2v[t*4+i]; s += v.x+v.y+v.z+v.w; }
        red[t] = s;
    }
    __syncthreads();
    if (t < 64) w2s[t] = red[t*4]+red[t*4+1]+red[t*4+2]+red[t*4+3];

    { // stage W1 -> hi/lo bf16, fragment-linear layout for mfma_16x16x32 B-frags
        const float* W1n = W1 + (size_t)n*4096;
        #pragma unroll
        for (int p = 0; p < 16; ++p){
            int idx = p*256 + t;            // coalesced read: d = idx>>6, e = idx&63
            float v = W1n[idx];
            int d = idx >> 6, e = idx & 63;
            int ss = d >> 5, j = d & 7, lg = (d >> 3) & 3;
            int ln = (lg << 4) | (e & 15);
            int dst = (((ss<<2) | (e>>4))*64 + ln)*8 + j;
            unsigned short h = f2bf(v);
            Bh[dst] = h;
            Bl[dst] = f2bf(v - bf2f(h));
        }
    }
    __syncthreads();

    // per-lane drug values at this lane's fixed d-offsets
    float dreg[2][8];
    {
        int d0 = (lane >> 4) << 3;
        #pragma unroll
        for (int ss = 0; ss < 2; ++ss)
            #pragma unroll
            for (int j = 0; j < 8; ++j)
                dreg[ss][j] = drug[ss*32 + d0 + j];
    }

    const int* arel = adj_rel + (size_t)n*KNB;
    const int kw = w * 256;   // wave's k-range [kw, kw+256)

    #pragma unroll 1
    for (int c = 0; c < 8; ++c){
        const int kb = kw + c*32;          // 32 k-rows per chunk (2 M-tiles)
        f32x4 acc[2][4] = {};

        #pragma unroll
        for (int ss = 0; ss < 2; ++ss){    // K-steps (d: 0..31, 32..63)
            short8 Ah[2], Al[2];
            #pragma unroll
            for (int m = 0; m < 2; ++m){
                int row = kb + m*16 + (lane & 15);
                int r = arel[row];
                const float* rp = rela_table + (size_t)r*64 + ss*32 + ((lane>>4)<<3);
                float4 v0 = *(const float4*)rp;
                float4 v1 = *(const float4*)(rp + 4);
                float xs[8] = {v0.x,v0.y,v0.z,v0.w,v1.x,v1.y,v1.z,v1.w};
                #pragma unroll
                for (int j = 0; j < 8; ++j){
                    float x = xs[j] * dreg[ss][j];   // drug_rel, exact fp32
                    unsigned short h = f2bf(x);
                    Ah[m][j] = (short)h;
                    Al[m][j] = (short)f2bf(x - bf2f(h));
                }
            }
            #pragma unroll
            for (int nn = 0; nn < 4; ++nn){
                int fb = (((ss<<2)|nn)*64 + lane)*8;
                short8 bh = *(const short8*)&Bh[fb];
                short8 bl = *(const short8*)&Bl[fb];
                #pragma unroll
                for (int m = 0; m < 2; ++m){
                    acc[m][nn] = __builtin_amdgcn_mfma_f32_16x16x32_bf16(Ah[m], bh, acc[m][nn], 0,0,0);
                    acc[m][nn] = __builtin_amdgcn_mfma_f32_16x16x32_bf16(Ah[m], bl, acc[m][nn], 0,0,0);
                    acc[m][nn] = __builtin_amdgcn_mfma_f32_16x16x32_bf16(Al[m], bh, acc[m][nn], 0,0,0);
                }
            }
        }

        // epilogue: s[k] = sum_e relu(H + b1) * w2sum[e]
        #pragma unroll
        for (int m = 0; m < 2; ++m){
            f32x4 sp = {0.f,0.f,0.f,0.f};
            int rbase = kb + m*16 + ((lane>>4)<<2);
            #pragma unroll
            for (int nn = 0; nn < 4; ++nn){
                int e = (nn<<4) | (lane & 15);
                float wv = w2s[e];
                #pragma unroll
                for (int q = 0; q < 4; ++q){
                    float h = acc[m][nn][q] + b1[(size_t)(rbase+q)*64 + e];
                    sp[q] += fmaxf(h, 0.f) * wv;
                }
            }
            #pragma unroll
            for (int off = 1; off < 16; off <<= 1){
                #pragma unroll
                for (int q = 0; q < 4; ++q)
                    sp[q] += __shfl_xor(sp[q], off, 64);
            }
            if ((lane & 15) == 0){
                #pragma unroll
                for (int q = 0; q < 4; ++q)
                    scores[rbase + q] = sp[q];
            }
        }
    }
    __syncthreads();

    // block softmax over 1024 scores (+ b2sum)
    float sv[4]; float mx = -1e30f;
    #pragma unroll
    for (int i = 0; i < 4; ++i){
        sv[i] = scores[t + i*256] + b2sum[t + i*256];
        mx = fmaxf(mx, sv[i]);
    }
    #pragma unroll
    for (int off = 1; off < 64; off <<= 1) mx = fmaxf(mx, __shfl_xor(mx, off, 64));
    if (lane == 0) red[w] = mx;
    __syncthreads();
    mx = fmaxf(fmaxf(red[0], red[1]), fmaxf(red[2], red[3]));
    float ps = 0.f;
    #pragma unroll
    for (int i = 0; i < 4; ++i){
        float e = __expf(sv[i] - mx);
        scores[t + i*256] = e;
        ps += e;
    }
    #pragma unroll
    for (int off = 1; off < 64; off <<= 1) ps += __shfl_xor(ps, off, 64);
    if (lane == 0) red[8 + w] = ps;
    __syncthreads();
    float inv = 1.f / (red[8]+red[9]+red[10]+red[11]);

    // weighted entity gather; skip exact-zero weights (exp underflow), wave-uniform
    const int* atail = adj_tail + (size_t)n*KNB;
    float awe = 0.f;
    for (int k = kw; k < kw + 256; ++k){
        float e = scores[k];
        if (e != 0.0f){
            int tl = atail[k];
            awe += e * ent_table[(size_t)tl*64 + lane];
        }
    }
    wepart[w][lane] = awe;
    __syncthreads();
    if (t < 64){
        de[t]    = (wepart[0][t]+wepart[1][t]+wepart[2][t]+wepart[3][t]) * inv;
        de[64+t] = drug[t];
    }
    __syncthreads();

    // y[j] = relu(lin_b[j] + sum_i de[i]*lin_w[j,i]); wave w covers i in [w*32, w*32+32)
    float yp = 0.f;
    #pragma unroll
    for (int ii = 0; ii < 32; ++ii){
        int i = w*32 + ii;
        yp += de[i] * lin_w[lane*128 + i];
    }
    red[t] = yp;
    __syncthreads();
    if (t < 64){
        float yv = lin_b[t] + red[t] + red[64+t] + red[128+t] + red[192+t];
        y_out[(size_t)n*64 + t] = fmaxf(yv, 0.f);
    }
}

__global__ void bn_kernel(const float* __restrict__ y, const float* __restrict__ bn_w,
                          const float* __restrict__ bn_b, float* __restrict__ out){
    __shared__ float r1[4], r2[4];
    const int j = blockIdx.x;
    const int t = threadIdx.x;
    float s1 = 0.f, s2 = 0.f;
    for (int i = t; i < NDRUG; i += 256){
        float v = y[(size_t)i*64 + j];
        s1 += v; s2 += v*v;
    }
    #pragma unroll
    for (int off = 1; off < 64; off <<= 1){
        s1 += __shfl_xor(s1, off, 64);
        s2 += __shfl_xor(s2, off, 64);
    }
    int w = t >> 6, lane = t & 63;
    if (lane == 0){ r1[w] = s1; r2[w] = s2; }
    __syncthreads();
    s1 = r1[0]+r1[1]+r1[2]+r1[3];
    s2 = r2[0]+r2[1]+r2[2]+r2[3];
    float mean = s1 * (1.f/NDRUG);
    float var  = s2 * (1.f/NDRUG) - mean*mean;   // biased (training-mode) variance
    float sc = rsqrtf(var + BN_EPS) * bn_w[j];
    float sh = bn_b[j] - mean*sc;
    for (int i = t; i < NDRUG; i += 256)
        out[(size_t)i*64 + j] = y[(size_t)i*64 + j]*sc + sh;
}

extern "C" void kernel_launch(void* const* d_in, const int* in_sizes, int n_in,
                              void* d_out, int out_size, void* d_ws, size_t ws_size,
                              hipStream_t stream) {
    const float* drug_table = (const float*)d_in[0];
    const float* rela_table = (const float*)d_in[1];
    const float* ent_table  = (const float*)d_in[2];
    const float* W1    = (const float*)d_in[3];
    const float* b1    = (const float*)d_in[4];
    const float* W2    = (const float*)d_in[5];
    const float* b2    = (const float*)d_in[6];
    const float* lin_w = (const float*)d_in[7];
    const float* lin_b = (const float*)d_in[8];
    const float* bn_w  = (const float*)d_in[9];
    const float* bn_b  = (const float*)d_in[10];
    const int* drug_name = (const int*)d_in[11];
    const int* adj_tail  = (const int*)d_in[12];
    const int* adj_rel   = (const int*)d_in[13];
    float* out = (float*)d_out;

    float* b2s = (float*)d_ws;          // [1024]
    float* yb  = b2s + KNB;             // [846*64]

    b2sum_kernel<<<KNB/256, 256, 0, stream>>>(b2, b2s);
    fused_gnn<<<NDRUG, 256, 0, stream>>>(drug_table, rela_table, ent_table, W1, b1, W2,
                                         lin_w, lin_b, drug_name, adj_tail, adj_rel, b2s, yb);
    bn_kernel<<<64, 256, 0, stream>>>(yb, bn_w, bn_b, out);
}